// Round 1
// baseline (18641.623 us; speedup 1.0000x reference)
//
#include <hip/hip_runtime.h>

typedef __attribute__((ext_vector_type(8))) short short8;   // 8 bf16 in 4 VGPRs
typedef __attribute__((ext_vector_type(4))) float f32x4;
typedef unsigned short u16;
typedef unsigned int u32;

static constexpr int TT = 512;
static constexpr int BB = 64;
static constexpr int HDim = 1024;
static constexpr int NBH = BB * HDim;          // 65536
static constexpr int NBLK = 128;               // scan blocks

__device__ __forceinline__ u16 f2bf(float f) {             // RNE f32->bf16
  u32 u = __float_as_uint(f);
  u32 r = u + 0x7FFFu + ((u >> 16) & 1u);
  return (u16)(r >> 16);
}
__device__ __forceinline__ float bf2f(u16 u) {
  return __uint_as_float(((u32)u) << 16);
}
__device__ __forceinline__ float sigmoidf_(float v) {
  return 1.0f / (1.0f + __expf(-v));
}

// ---------------- prep: Wih->bf16, V0 = x[0] + g*Q0, zero barrier ----------
__global__ void prep_kernel(const float* __restrict__ x, const float* __restrict__ Q0,
                            const float* __restrict__ Wih, const float* __restrict__ uVr,
                            const float* __restrict__ uV2,
                            u16* __restrict__ Wih_bf, u16* __restrict__ V0,
                            u32* __restrict__ bar) {
  const int NW = 2048 * 1024;
  int stride = gridDim.x * blockDim.x;
  int gid = blockIdx.x * blockDim.x + threadIdx.x;
  if (gid == 0) { bar[0] = 0u; bar[1] = 0u; }
  for (int i = gid; i < NW; i += stride) Wih_bf[i] = f2bf(Wih[i]);
  for (int j = gid; j < NBH; j += stride) {
    int h = j & (HDim - 1);
    float g = sigmoidf_(uV2[h]) * tanhf(uVr[h]);
    V0[j] = f2bf(x[j] + g * Q0[j]);
  }
}

// ---------------- A_all = x @ WA^T  (M=32768,N=1024,K=1024), bf16 out ------
__global__ __launch_bounds__(256) void agemm_kernel(const float* __restrict__ X,
                                                    const float* __restrict__ W,
                                                    u16* __restrict__ C) {
  __shared__ u16 As[128 * 64];
  __shared__ u16 Bs[128 * 64];
  int tid = threadIdx.x;
  int l = tid & 63, w = tid >> 6;
  int n = l & 15, rowg = l >> 4;
  int wr = w >> 1, wc = w & 1;
  int bm = blockIdx.x >> 3, bn = blockIdx.x & 7;
  long m0 = (long)bm * 128;
  int n0 = bn * 128;
  int srow = tid >> 4;        // 0..15
  int sk4 = (tid & 15) * 4;   // 0..60

  f32x4 acc[4][4];
#pragma unroll
  for (int r = 0; r < 4; ++r)
#pragma unroll
    for (int c = 0; c < 4; ++c) acc[r][c] = (f32x4){0.f, 0.f, 0.f, 0.f};

  for (int kt = 0; kt < 16; ++kt) {
    __syncthreads();
#pragma unroll
    for (int i = 0; i < 8; ++i) {
      int row = srow + i * 16;
      float4 va = *(const float4*)(X + (m0 + row) * 1024 + kt * 64 + sk4);
      u32 lo = (u32)f2bf(va.x) | ((u32)f2bf(va.y) << 16);
      u32 hi = (u32)f2bf(va.z) | ((u32)f2bf(va.w) << 16);
      *(uint2*)(As + row * 64 + sk4) = make_uint2(lo, hi);
      float4 vb = *(const float4*)(W + (long)(n0 + row) * 1024 + kt * 64 + sk4);
      u32 lo2 = (u32)f2bf(vb.x) | ((u32)f2bf(vb.y) << 16);
      u32 hi2 = (u32)f2bf(vb.z) | ((u32)f2bf(vb.w) << 16);
      *(uint2*)(Bs + row * 64 + sk4) = make_uint2(lo2, hi2);
    }
    __syncthreads();
#pragma unroll
    for (int ks = 0; ks < 2; ++ks) {
      short8 af[4], bfr[4];
#pragma unroll
      for (int r = 0; r < 4; ++r)
        af[r] = *(const short8*)(As + (wr * 64 + r * 16 + n) * 64 + ks * 32 + rowg * 8);
#pragma unroll
      for (int c = 0; c < 4; ++c)
        bfr[c] = *(const short8*)(Bs + (wc * 64 + c * 16 + n) * 64 + ks * 32 + rowg * 8);
#pragma unroll
      for (int r = 0; r < 4; ++r)
#pragma unroll
        for (int c = 0; c < 4; ++c)
          acc[r][c] = __builtin_amdgcn_mfma_f32_16x16x32_bf16(af[r], bfr[c], acc[r][c], 0, 0, 0);
    }
  }
#pragma unroll
  for (int r = 0; r < 4; ++r)
#pragma unroll
    for (int c = 0; c < 4; ++c)
#pragma unroll
      for (int q = 0; q < 4; ++q) {
        long row = m0 + wr * 64 + r * 16 + rowg * 4 + q;
        int col = n0 + wc * 64 + c * 16 + n;
        C[row * 1024 + col] = f2bf(acc[r][c][q]);
      }
}

// ---------------- persistent scan ------------------------------------------
// 128 blocks x 256 thr. Block bk owns h in [bk*8, bk*8+8) -> computes Fi rows
// h and Ri rows 1024+h of Wih for all 64 batch rows. Wave w owns batch rows
// [w*16, w*16+16). Weights held in 128 VGPRs/wave across all 512 steps.
__global__ __launch_bounds__(256, 1) void scan_kernel(
    const u16* __restrict__ Wih_bf, const u16* __restrict__ A_bf,
    const float* __restrict__ x, const float* __restrict__ S0,
    const float* __restrict__ PFB, const float* __restrict__ HWb,
    const float* __restrict__ uVr, const float* __restrict__ uV2,
    u16* __restrict__ Vws, float* __restrict__ out, u32* __restrict__ bar) {
  int tid = threadIdx.x, bk = blockIdx.x;
  int l = tid & 63, w = tid >> 6;
  int n = l & 15, rowg = l >> 4;
  int hloc = n & 7;
  int h = bk * 8 + hloc;
  bool isF = (n < 8);
  int jrow = isF ? h : (1024 + h);
  int bw = w * 16;

  // Weight fragments: B-operand lane l holds W[jrow(n)][k], k=(l>>4)*8+e
  short8 breg[32];
  const u16* wp = Wih_bf + (long)jrow * 1024 + rowg * 8;
#pragma unroll
  for (int kk = 0; kk < 32; ++kk) breg[kk] = *(const short8*)(wp + kk * 32);

  float pfb = PFB[h], hwb = HWb[h];
  float gh = sigmoidf_(uV2[h]) * tanhf(uVr[h]);

  int rowoff[4];
  float S[4];
#pragma unroll
  for (int r = 0; r < 4; ++r) {
    rowoff[r] = (bw + rowg * 4 + r) * 1024 + h;
    S[r] = S0[rowoff[r]];
  }
  const int vrow = (bw + n) * 1024 + rowg * 8;   // A-operand: row=l&15, k=(l>>4)*8

#pragma unroll 1
  for (int t = 0; t < TT; ++t) {
    const u16* V = Vws + (t & 1) * NBH + vrow;
    f32x4 pa[4];
#pragma unroll
    for (int i = 0; i < 4; ++i) pa[i] = (f32x4){0.f, 0.f, 0.f, 0.f};
#pragma unroll
    for (int kk = 0; kk < 32; ++kk) {
      short8 af = *(const short8*)(V + kk * 32);
      pa[kk & 3] = __builtin_amdgcn_mfma_f32_16x16x32_bf16(af, breg[kk], pa[kk & 3], 0, 0, 0);
    }
    f32x4 acc = pa[0] + pa[1] + pa[2] + pa[3];

    u16* Vn = Vws + ((t + 1) & 1) * NBH;
    long tbase = (long)t * NBH;
#pragma unroll
    for (int r = 0; r < 4; ++r) {
      float mine = acc[r];
      float other = __shfl_xor(mine, 8, 64);
      float Fi = isF ? mine : other;
      float Ri = isF ? other : mine;
      float F = sigmoidf_(Fi + pfb);
      float Rg = sigmoidf_(Ri + hwb);
      long off = tbase + rowoff[r];
      float Av = bf2f(A_bf[off]);
      S[r] = F * S[r] + (1.0f - F) * Av;
      float Q = Rg * S[r] + (1.0f - Rg) * x[off];
      if (isF) {
        out[off] = Q;
        if (t < TT - 1) {
          Vn[rowoff[r]] = f2bf(x[off + NBH] + gh * Q);
        } else {
          out[(long)TT * NBH + rowoff[r]] = Q;          // Qf
          out[(long)TT * NBH + NBH + rowoff[r]] = S[r]; // Sf
        }
      }
    }
    if (t == TT - 1) break;

    // one device-wide barrier per step (ping-pong V makes one sufficient)
    __threadfence();
    __syncthreads();
    if (tid == 0) {
      u32 target = (u32)(NBLK * (t + 1));
      u32 old = __hip_atomic_fetch_add(&bar[0], 1u, __ATOMIC_ACQ_REL, __HIP_MEMORY_SCOPE_AGENT);
      if (old == target - 1u)
        __hip_atomic_store(&bar[1], target, __ATOMIC_RELEASE, __HIP_MEMORY_SCOPE_AGENT);
      while (__hip_atomic_load(&bar[1], __ATOMIC_ACQUIRE, __HIP_MEMORY_SCOPE_AGENT) < target)
        __builtin_amdgcn_s_sleep(1);
    }
    __syncthreads();
    __threadfence();   // acquire: invalidate L1 so fresh V is read
  }
}

extern "C" void kernel_launch(void* const* d_in, const int* in_sizes, int n_in,
                              void* d_out, int out_size, void* d_ws, size_t ws_size,
                              hipStream_t stream) {
  const float* x   = (const float*)d_in[0];
  const float* Q0  = (const float*)d_in[1];
  const float* S0  = (const float*)d_in[2];
  const float* Wih = (const float*)d_in[3];
  const float* WA  = (const float*)d_in[4];
  const float* uVr = (const float*)d_in[5];
  const float* uV2 = (const float*)d_in[6];
  const float* PFB = (const float*)d_in[7];
  const float* HWb = (const float*)d_in[8];
  float* out = (float*)d_out;

  char* ws = (char*)d_ws;
  u16* A_bf   = (u16*)(ws);                 // 67,108,864 B : A_all bf16 [T*B][HD]
  u16* Wih_bf = (u16*)(ws + 67108864);      //  4,194,304 B
  u16* Vws    = (u16*)(ws + 71303168);      //    262,144 B : ping-pong V
  u32* bar    = (u32*)(ws + 71565312);      //         64 B : barrier cnt+flag
  (void)in_sizes; (void)n_in; (void)out_size; (void)ws_size;

  prep_kernel<<<2048, 256, 0, stream>>>(x, Q0, Wih, uVr, uV2, Wih_bf, Vws, bar);
  agemm_kernel<<<2048, 256, 0, stream>>>(x, WA, A_bf);
  scan_kernel<<<NBLK, 256, 0, stream>>>(Wih_bf, A_bf, x, S0, PFB, HWb, uVr, uV2, Vws, out, bar);
}

// Round 2
// 4784.241 us; speedup vs baseline: 3.8965x; 3.8965x over previous
//
#include <hip/hip_runtime.h>

typedef __attribute__((ext_vector_type(8))) short short8;   // 8 bf16 in 4 VGPRs
typedef __attribute__((ext_vector_type(4))) float f32x4;
typedef __attribute__((ext_vector_type(4))) unsigned int u32x4;
typedef unsigned short u16;
typedef unsigned int u32;

static constexpr int TT = 512;
static constexpr int HDim = 1024;
static constexpr int NBH = 64 * 1024;          // B*HD = 65536
static constexpr int NBLK = 128;               // scan blocks

__device__ __forceinline__ u16 f2bf(float f) {             // RNE f32->bf16
  u32 u = __float_as_uint(f);
  u32 r = u + 0x7FFFu + ((u >> 16) & 1u);
  return (u16)(r >> 16);
}
__device__ __forceinline__ float bf2f(u16 u) {
  return __uint_as_float(((u32)u) << 16);
}
__device__ __forceinline__ float sigmoidf_(float v) {
  return 1.0f / (1.0f + __expf(-v));
}

// agent-coherent (sc1) memory ops: bypass non-coherent per-XCD L2s
#define VLOADX4_SC1(dst, addr) \
  asm volatile("global_load_dwordx4 %0, %1, off sc1" : "=v"(dst) : "v"(addr) : "memory")
#define STORE_U32_SC1(addr, val) \
  asm volatile("global_store_dword %0, %1, off sc1" :: "v"(addr), "v"(val) : "memory")
#define WAITVM(n) asm volatile("s_waitcnt vmcnt(" #n ")" ::: "memory")

// ---------------- prep: Wih->bf16, V0 = x[0] + g*Q0, zero flags ------------
__global__ void prep_kernel(const float* __restrict__ x, const float* __restrict__ Q0,
                            const float* __restrict__ Wih, const float* __restrict__ uVr,
                            const float* __restrict__ uV2,
                            u16* __restrict__ Wih_bf, u16* __restrict__ V0,
                            u32* __restrict__ flags) {
  const int NW = 2048 * 1024;
  int stride = gridDim.x * blockDim.x;
  int gid = blockIdx.x * blockDim.x + threadIdx.x;
  if (gid < NBLK) flags[gid] = 0u;
  for (int i = gid; i < NW; i += stride) Wih_bf[i] = f2bf(Wih[i]);
  for (int j = gid; j < NBH; j += stride) {
    int h = j & (HDim - 1);
    float g = sigmoidf_(uV2[h]) * tanhf(uVr[h]);
    V0[j] = f2bf(x[j] + g * Q0[j]);
  }
}

// ---------------- A_all = x @ WA^T  (M=32768,N=1024,K=1024), bf16 out ------
__global__ __launch_bounds__(256) void agemm_kernel(const float* __restrict__ X,
                                                    const float* __restrict__ W,
                                                    u16* __restrict__ C) {
  __shared__ u16 As[128 * 64];
  __shared__ u16 Bs[128 * 64];
  int tid = threadIdx.x;
  int l = tid & 63, w = tid >> 6;
  int n = l & 15, rowg = l >> 4;
  int wr = w >> 1, wc = w & 1;
  int bm = blockIdx.x >> 3, bn = blockIdx.x & 7;
  long m0 = (long)bm * 128;
  int n0 = bn * 128;
  int srow = tid >> 4;        // 0..15
  int sk4 = (tid & 15) * 4;   // 0..60

  f32x4 acc[4][4];
#pragma unroll
  for (int r = 0; r < 4; ++r)
#pragma unroll
    for (int c = 0; c < 4; ++c) acc[r][c] = (f32x4){0.f, 0.f, 0.f, 0.f};

  for (int kt = 0; kt < 16; ++kt) {
    __syncthreads();
#pragma unroll
    for (int i = 0; i < 8; ++i) {
      int row = srow + i * 16;
      float4 va = *(const float4*)(X + (m0 + row) * 1024 + kt * 64 + sk4);
      u32 lo = (u32)f2bf(va.x) | ((u32)f2bf(va.y) << 16);
      u32 hi = (u32)f2bf(va.z) | ((u32)f2bf(va.w) << 16);
      *(uint2*)(As + row * 64 + sk4) = make_uint2(lo, hi);
      float4 vb = *(const float4*)(W + (long)(n0 + row) * 1024 + kt * 64 + sk4);
      u32 lo2 = (u32)f2bf(vb.x) | ((u32)f2bf(vb.y) << 16);
      u32 hi2 = (u32)f2bf(vb.z) | ((u32)f2bf(vb.w) << 16);
      *(uint2*)(Bs + row * 64 + sk4) = make_uint2(lo2, hi2);
    }
    __syncthreads();
#pragma unroll
    for (int ks = 0; ks < 2; ++ks) {
      short8 af[4], bfr[4];
#pragma unroll
      for (int r = 0; r < 4; ++r)
        af[r] = *(const short8*)(As + (wr * 64 + r * 16 + n) * 64 + ks * 32 + rowg * 8);
#pragma unroll
      for (int c = 0; c < 4; ++c)
        bfr[c] = *(const short8*)(Bs + (wc * 64 + c * 16 + n) * 64 + ks * 32 + rowg * 8);
#pragma unroll
      for (int r = 0; r < 4; ++r)
#pragma unroll
        for (int c = 0; c < 4; ++c)
          acc[r][c] = __builtin_amdgcn_mfma_f32_16x16x32_bf16(af[r], bfr[c], acc[r][c], 0, 0, 0);
    }
  }
#pragma unroll
  for (int r = 0; r < 4; ++r)
#pragma unroll
    for (int c = 0; c < 4; ++c)
#pragma unroll
      for (int q = 0; q < 4; ++q) {
        long row = m0 + wr * 64 + r * 16 + rowg * 4 + q;
        int col = n0 + wc * 64 + c * 16 + n;
        C[row * 1024 + col] = f2bf(acc[r][c][q]);
      }
}

// ---------------- persistent scan ------------------------------------------
// 128 blocks x 256 thr, 1 block/CU. Block bk owns h in [bk*8, bk*8+8):
// computes Fi rows h and Ri rows 1024+h of Wih for all 64 batch rows.
// Weights pinned in 128 VGPRs/wave for all 512 steps. Cross-block sync:
// per-block monotone flag (sc1), V data via sc1 stores/loads (no L2 flush).
__global__ __launch_bounds__(256, 1) void scan_kernel(
    const u16* __restrict__ Wih_bf, const u16* __restrict__ A_bf,
    const float* __restrict__ x, const float* __restrict__ S0,
    const float* __restrict__ PFB, const float* __restrict__ HWb,
    const float* __restrict__ uVr, const float* __restrict__ uV2,
    u16* __restrict__ Vws, float* __restrict__ out, u32* __restrict__ flags) {
  const int tid = threadIdx.x, bk = blockIdx.x;
  const int l = tid & 63, w = tid >> 6;
  const int n = l & 15, rowg = l >> 4;
  const int hloc = n & 7;
  const int h = bk * 8 + hloc;
  const bool isF = (n < 8);
  const int jrow = isF ? h : (HDim + h);
  const int bw = w * 16;

  // B-operand weight fragments: lane l holds W[jrow(n)][k], k=(l>>4)*8+e
  short8 breg[32];
  {
    const u16* wp = Wih_bf + (long)jrow * 1024 + rowg * 8;
#pragma unroll
    for (int kk = 0; kk < 32; ++kk) breg[kk] = *(const short8*)(wp + kk * 32);
#pragma unroll
    for (int kk = 0; kk < 32; ++kk) asm volatile("" : "+v"(breg[kk]));  // pin in VGPRs
  }

  const float pfb = PFB[h], hwb = HWb[h];
  const float gh = sigmoidf_(uV2[h]) * tanhf(uVr[h]);

  int rowoff[4];
  float S[4];
#pragma unroll
  for (int r = 0; r < 4; ++r) {
    rowoff[r] = (bw + rowg * 4 + r) * 1024 + h;
    S[r] = S0[rowoff[r]];
  }
  const int vrow = (bw + n) * 1024 + rowg * 8;   // A-operand: row=l&15, k=(l>>4)*8

  // prefetch step-0 scalars
  float xq[4], xn[4], av[4];
#pragma unroll
  for (int r = 0; r < 4; ++r) {
    xq[r] = x[rowoff[r]];
    xn[r] = x[NBH + rowoff[r]];
    av[r] = bf2f(A_bf[rowoff[r]]);
  }

#pragma unroll 1
  for (int t = 0; t < TT; ++t) {
    // ---- wait until all blocks produced V[t] (and are done reading V[t-1])
    if (t > 0) {
      if (w == 0 && l < 32) {
        const u32* fp = flags + l * 4;
        const u32 tv = (u32)t;
        while (true) {
          u32x4 fv;
          VLOADX4_SC1(fv, fp);
          WAITVM(0);
          __builtin_amdgcn_sched_barrier(0);
          if (fv[0] >= tv && fv[1] >= tv && fv[2] >= tv && fv[3] >= tv) break;
        }
      }
      __syncthreads();
    }

    // ---- FR = V[t] @ Wih^T fragment: 32 MFMAs, loads pipelined 4-deep
    const u16* vp = Vws + (t & 1) * NBH + vrow;
    f32x4 pa[4];
#pragma unroll
    for (int i = 0; i < 4; ++i) pa[i] = (f32x4){0.f, 0.f, 0.f, 0.f};

    short8 va[2][4];
#pragma unroll
    for (int i = 0; i < 4; ++i) VLOADX4_SC1(va[0][i], vp + i * 32);
#pragma unroll
    for (int g = 0; g < 8; ++g) {
      const int cur = g & 1, nxt = cur ^ 1;
      if (g < 7) {
#pragma unroll
        for (int i = 0; i < 4; ++i) VLOADX4_SC1(va[nxt][i], vp + ((g + 1) * 4 + i) * 32);
        WAITVM(4);
      } else {
        WAITVM(0);
      }
      __builtin_amdgcn_sched_barrier(0);
#pragma unroll
      for (int i = 0; i < 4; ++i)
        pa[i] = __builtin_amdgcn_mfma_f32_16x16x32_bf16(va[cur][i], breg[g * 4 + i], pa[i], 0, 0, 0);
    }
    f32x4 acc = pa[0] + pa[1] + pa[2] + pa[3];

    // ---- gates, state update, stores
    u16* vnext = Vws + ((t + 1) & 1) * NBH;
    const long tbase = (long)t * NBH;
#pragma unroll
    for (int r = 0; r < 4; ++r) {
      float mine = acc[r];
      float other = __shfl_xor(mine, 8, 64);
      float Fi = isF ? mine : other;
      float Ri = isF ? other : mine;
      float F = sigmoidf_(Fi + pfb);
      float Rg = sigmoidf_(Ri + hwb);
      const long off = tbase + rowoff[r];
      S[r] = F * S[r] + (1.0f - F) * av[r];
      float Q = Rg * S[r] + (1.0f - Rg) * xq[r];
      if (isF) {
        out[off] = Q;                         // Y (cached store)
        if (t < TT - 1) {
          u32 word = (u32)f2bf(xn[r] + gh * Q);
          u32 othw = (u32)__shfl_xor((int)word, 1, 64);
          if ((hloc & 1) == 0) {              // pack pair -> one dword sc1 store
            u32 packed = word | (othw << 16);
            STORE_U32_SC1(vnext + rowoff[r], packed);
          }
        } else {
          out[(long)TT * NBH + rowoff[r]] = Q;           // Qf
          out[(long)TT * NBH + NBH + rowoff[r]] = S[r];  // Sf
        }
      }
    }

    if (t < TT - 1) {
      // ---- prefetch next step's scalars (overlaps with store drain)
      const long nb = tbase + NBH;
      const int tn = (t + 2 < TT) ? (t + 2) : (TT - 1);
      const long nb2 = (long)tn * NBH;
#pragma unroll
      for (int r = 0; r < 4; ++r) {
        xq[r] = x[nb + rowoff[r]];
        av[r] = bf2f(A_bf[nb + rowoff[r]]);
        xn[r] = x[nb2 + rowoff[r]];
      }
      // ---- signal: per-wave drain, block-wide join, one flag store
      WAITVM(0);
      __syncthreads();
      if (tid == 0) {
        u32 tv = (u32)(t + 1);
        STORE_U32_SC1(flags + bk, tv);
      }
    }
  }
}

extern "C" void kernel_launch(void* const* d_in, const int* in_sizes, int n_in,
                              void* d_out, int out_size, void* d_ws, size_t ws_size,
                              hipStream_t stream) {
  const float* x   = (const float*)d_in[0];
  const float* Q0  = (const float*)d_in[1];
  const float* S0  = (const float*)d_in[2];
  const float* Wih = (const float*)d_in[3];
  const float* WA  = (const float*)d_in[4];
  const float* uVr = (const float*)d_in[5];
  const float* uV2 = (const float*)d_in[6];
  const float* PFB = (const float*)d_in[7];
  const float* HWb = (const float*)d_in[8];
  float* out = (float*)d_out;

  char* ws = (char*)d_ws;
  u16* A_bf   = (u16*)(ws);                 // 67,108,864 B : A_all bf16 [T*B][HD]
  u16* Wih_bf = (u16*)(ws + 67108864);      //  4,194,304 B
  u16* Vws    = (u16*)(ws + 71303168);      //    262,144 B : ping-pong V (bf16)
  u32* flags  = (u32*)(ws + 71565312);      //        512 B : per-block step flags
  (void)in_sizes; (void)n_in; (void)out_size; (void)ws_size;

  prep_kernel<<<2048, 256, 0, stream>>>(x, Q0, Wih, uVr, uV2, Wih_bf, Vws, flags);
  agemm_kernel<<<2048, 256, 0, stream>>>(x, WA, A_bf);
  scan_kernel<<<NBLK, 256, 0, stream>>>(Wih_bf, A_bf, x, S0, PFB, HWb, uVr, uV2, Vws, out, flags);
}

// Round 3
// 2424.139 us; speedup vs baseline: 7.6900x; 1.9736x over previous
//
#include <hip/hip_runtime.h>

typedef __attribute__((ext_vector_type(8))) short short8;   // 8 bf16 in 4 VGPRs
typedef __attribute__((ext_vector_type(4))) float f32x4;
typedef __attribute__((ext_vector_type(4))) unsigned int u32x4;
typedef unsigned short u16;
typedef unsigned int u32;

static constexpr int TT = 512;
static constexpr int HDim = 1024;
static constexpr int NBH = 64 * 1024;          // B*HD = 65536
static constexpr int NBLK = 128;               // scan blocks: 4 bg x 32 hg

__device__ __forceinline__ u16 f2bf(float f) {             // RNE f32->bf16
  u32 u = __float_as_uint(f);
  u32 r = u + 0x7FFFu + ((u >> 16) & 1u);
  return (u16)(r >> 16);
}
__device__ __forceinline__ float bf2f(u16 u) {
  return __uint_as_float(((u32)u) << 16);
}
__device__ __forceinline__ float sigmoidf_(float v) {
  return 1.0f / (1.0f + __expf(-v));
}

// agent-coherent (sc1) memory ops: bypass non-coherent per-XCD L2s
#define VLOADX4_SC1(dst, addr) \
  asm volatile("global_load_dwordx4 %0, %1, off sc1" : "=v"(dst) : "v"(addr) : "memory")
#define STORE_U32_SC1(addr, val) \
  asm volatile("global_store_dword %0, %1, off sc1" :: "v"(addr), "v"(val) : "memory")
#define WAITVM(n) asm volatile("s_waitcnt vmcnt(" #n ")" ::: "memory")
#define SBAR() __builtin_amdgcn_sched_barrier(0)

// ---------------- prep: Wih->bf16, V0 = x[0] + g*Q0, zero flags ------------
__global__ void prep_kernel(const float* __restrict__ x, const float* __restrict__ Q0,
                            const float* __restrict__ Wih, const float* __restrict__ uVr,
                            const float* __restrict__ uV2,
                            u16* __restrict__ Wih_bf, u16* __restrict__ V0,
                            u32* __restrict__ flags) {
  const int NW = 2048 * 1024;
  int stride = gridDim.x * blockDim.x;
  int gid = blockIdx.x * blockDim.x + threadIdx.x;
  if (gid < NBLK) flags[gid] = 0u;
  for (int i = gid; i < NW; i += stride) Wih_bf[i] = f2bf(Wih[i]);
  for (int j = gid; j < NBH; j += stride) {
    int h = j & (HDim - 1);
    float g = sigmoidf_(uV2[h]) * tanhf(uVr[h]);
    V0[j] = f2bf(x[j] + g * Q0[j]);
  }
}

// ---------------- A_all = x @ WA^T  (M=32768,N=1024,K=1024), bf16 out ------
__global__ __launch_bounds__(256) void agemm_kernel(const float* __restrict__ X,
                                                    const float* __restrict__ W,
                                                    u16* __restrict__ C) {
  __shared__ u16 As[128 * 64];
  __shared__ u16 Bs[128 * 64];
  int tid = threadIdx.x;
  int l = tid & 63, w = tid >> 6;
  int n = l & 15, rowg = l >> 4;
  int wr = w >> 1, wc = w & 1;
  int bm = blockIdx.x >> 3, bn = blockIdx.x & 7;
  long m0 = (long)bm * 128;
  int n0 = bn * 128;
  int srow = tid >> 4;        // 0..15
  int sk4 = (tid & 15) * 4;   // 0..60

  f32x4 acc[4][4];
#pragma unroll
  for (int r = 0; r < 4; ++r)
#pragma unroll
    for (int c = 0; c < 4; ++c) acc[r][c] = (f32x4){0.f, 0.f, 0.f, 0.f};

  for (int kt = 0; kt < 16; ++kt) {
    __syncthreads();
#pragma unroll
    for (int i = 0; i < 8; ++i) {
      int row = srow + i * 16;
      float4 va = *(const float4*)(X + (m0 + row) * 1024 + kt * 64 + sk4);
      u32 lo = (u32)f2bf(va.x) | ((u32)f2bf(va.y) << 16);
      u32 hi = (u32)f2bf(va.z) | ((u32)f2bf(va.w) << 16);
      *(uint2*)(As + row * 64 + sk4) = make_uint2(lo, hi);
      float4 vb = *(const float4*)(W + (long)(n0 + row) * 1024 + kt * 64 + sk4);
      u32 lo2 = (u32)f2bf(vb.x) | ((u32)f2bf(vb.y) << 16);
      u32 hi2 = (u32)f2bf(vb.z) | ((u32)f2bf(vb.w) << 16);
      *(uint2*)(Bs + row * 64 + sk4) = make_uint2(lo2, hi2);
    }
    __syncthreads();
#pragma unroll
    for (int ks = 0; ks < 2; ++ks) {
      short8 af[4], bfr[4];
#pragma unroll
      for (int r = 0; r < 4; ++r)
        af[r] = *(const short8*)(As + (wr * 64 + r * 16 + n) * 64 + ks * 32 + rowg * 8);
#pragma unroll
      for (int c = 0; c < 4; ++c)
        bfr[c] = *(const short8*)(Bs + (wc * 64 + c * 16 + n) * 64 + ks * 32 + rowg * 8);
#pragma unroll
      for (int r = 0; r < 4; ++r)
#pragma unroll
        for (int c = 0; c < 4; ++c)
          acc[r][c] = __builtin_amdgcn_mfma_f32_16x16x32_bf16(af[r], bfr[c], acc[r][c], 0, 0, 0);
    }
  }
#pragma unroll
  for (int r = 0; r < 4; ++r)
#pragma unroll
    for (int c = 0; c < 4; ++c)
#pragma unroll
      for (int q = 0; q < 4; ++q) {
        long row = m0 + wr * 64 + r * 16 + rowg * 4 + q;
        int col = n0 + wc * 64 + c * 16 + n;
        C[row * 1024 + col] = f2bf(acc[r][c][q]);
      }
}

// ---------------- persistent scan ------------------------------------------
// 128 blocks = 4 batch-groups (16 rows) x 32 h-groups (32 h). Block needs only
// V[its 16 batch rows][all 1024 k] = 32 KB/step; sync is batch-group-local
// (32 flags). Waves K-split (256 k each, distinct bytes); partial FR reduced
// via 16 KB LDS. Weights: 32 named short8 = 128 VGPR/wave, resident all steps.
#define MFMA(a, b, c) __builtin_amdgcn_mfma_f32_16x16x32_bf16(a, b, c, 0, 0, 0)
#define VLD(kk) VLOADX4_SC1(v##kk, vp + kk * 32)
#define MFMA_STEP(kk, VM)                      \
  WAITVM(VM); SBAR();                          \
  pa0 = MFMA(v##kk, b0##kk, pa0);              \
  pa1 = MFMA(v##kk, b1##kk, pa1);              \
  pa2 = MFMA(v##kk, b2##kk, pa2);              \
  pa3 = MFMA(v##kk, b3##kk, pa3);

__global__ __attribute__((amdgpu_flat_work_group_size(256, 256), amdgpu_waves_per_eu(1, 1)))
void scan_kernel(
    const u16* __restrict__ Wih_bf, const u16* __restrict__ A_bf,
    const float* __restrict__ x, const float* __restrict__ S0,
    const float* __restrict__ PFB, const float* __restrict__ HWb,
    const float* __restrict__ uVr, const float* __restrict__ uV2,
    u16* __restrict__ Vws, float* __restrict__ out, u32* __restrict__ flags) {
  const int tid = threadIdx.x, bk = blockIdx.x;
  const int bg = bk >> 5, hg = bk & 31;
  const int l = tid & 63, w = tid >> 6;
  const int n = l & 15, rowg = l >> 4;
  const int hl = n & 7;
  const int h = hg * 32 + w * 8 + hl;        // this wave's output h column
  const bool isF = (n < 8);

  __shared__ f32x4 red[16][64];              // [jt*4+wave][lane]

  const int kbase = w * 256 + rowg * 8;      // this wave's K-quarter fragment
  // weight fragments: B[k][j(n)] = Wih[j][k]; tile jt covers h = hg*32+jt*8+hl
  const u16* wp0 = Wih_bf + (long)((isF ? 0 : 1024) + hg * 32 + 0 + hl) * 1024 + kbase;
  const u16* wp1 = Wih_bf + (long)((isF ? 0 : 1024) + hg * 32 + 8 + hl) * 1024 + kbase;
  const u16* wp2 = Wih_bf + (long)((isF ? 0 : 1024) + hg * 32 + 16 + hl) * 1024 + kbase;
  const u16* wp3 = Wih_bf + (long)((isF ? 0 : 1024) + hg * 32 + 24 + hl) * 1024 + kbase;
  short8 b00 = *(const short8*)(wp0 + 0 * 32), b01 = *(const short8*)(wp0 + 1 * 32),
         b02 = *(const short8*)(wp0 + 2 * 32), b03 = *(const short8*)(wp0 + 3 * 32),
         b04 = *(const short8*)(wp0 + 4 * 32), b05 = *(const short8*)(wp0 + 5 * 32),
         b06 = *(const short8*)(wp0 + 6 * 32), b07 = *(const short8*)(wp0 + 7 * 32);
  short8 b10 = *(const short8*)(wp1 + 0 * 32), b11 = *(const short8*)(wp1 + 1 * 32),
         b12 = *(const short8*)(wp1 + 2 * 32), b13 = *(const short8*)(wp1 + 3 * 32),
         b14 = *(const short8*)(wp1 + 4 * 32), b15 = *(const short8*)(wp1 + 5 * 32),
         b16 = *(const short8*)(wp1 + 6 * 32), b17 = *(const short8*)(wp1 + 7 * 32);
  short8 b20 = *(const short8*)(wp2 + 0 * 32), b21 = *(const short8*)(wp2 + 1 * 32),
         b22 = *(const short8*)(wp2 + 2 * 32), b23 = *(const short8*)(wp2 + 3 * 32),
         b24 = *(const short8*)(wp2 + 4 * 32), b25 = *(const short8*)(wp2 + 5 * 32),
         b26 = *(const short8*)(wp2 + 6 * 32), b27 = *(const short8*)(wp2 + 7 * 32);
  short8 b30 = *(const short8*)(wp3 + 0 * 32), b31 = *(const short8*)(wp3 + 1 * 32),
         b32 = *(const short8*)(wp3 + 2 * 32), b33 = *(const short8*)(wp3 + 3 * 32),
         b34 = *(const short8*)(wp3 + 4 * 32), b35 = *(const short8*)(wp3 + 5 * 32),
         b36 = *(const short8*)(wp3 + 6 * 32), b37 = *(const short8*)(wp3 + 7 * 32);
  asm volatile("" : "+v"(b00), "+v"(b01), "+v"(b02), "+v"(b03), "+v"(b04), "+v"(b05), "+v"(b06), "+v"(b07));
  asm volatile("" : "+v"(b10), "+v"(b11), "+v"(b12), "+v"(b13), "+v"(b14), "+v"(b15), "+v"(b16), "+v"(b17));
  asm volatile("" : "+v"(b20), "+v"(b21), "+v"(b22), "+v"(b23), "+v"(b24), "+v"(b25), "+v"(b26), "+v"(b27));
  asm volatile("" : "+v"(b30), "+v"(b31), "+v"(b32), "+v"(b33), "+v"(b34), "+v"(b35), "+v"(b36), "+v"(b37));

  const float pfb = PFB[h], hwb = HWb[h];
  const float gh = sigmoidf_(uV2[h]) * tanhf(uVr[h]);

  int rowoff[4];
  float S[4];
#pragma unroll
  for (int r = 0; r < 4; ++r) {
    rowoff[r] = (bg * 16 + rowg * 4 + r) * 1024 + h;
    S[r] = S0[rowoff[r]];
  }
  const int vbase = (bg * 16 + n) * 1024 + kbase;   // A-operand fragment addr
  const u32* fp = flags + bg * 32 + ((l & 7) << 2); // 4 flags of my bg per lane

  float xq[4], xn[4], av[4];
#pragma unroll
  for (int r = 0; r < 4; ++r) {
    xq[r] = x[rowoff[r]];
    xn[r] = x[NBH + rowoff[r]];
    av[r] = bf2f(A_bf[rowoff[r]]);
  }

#pragma unroll 1
  for (int t = 0; t < TT; ++t) {
    // ---- per-wave poll: all 32 producers of my batch group reached step t
    if (t > 0) {
      const u32 tv = (u32)t;
      while (true) {
        u32x4 fv;
        VLOADX4_SC1(fv, fp);
        WAITVM(0);
        SBAR();
        bool ok = fv[0] >= tv && fv[1] >= tv && fv[2] >= tv && fv[3] >= tv;
        if (__all(ok)) break;
      }
    }

    // ---- partial FR over this wave's K-quarter: all 8 loads in flight
    const u16* vp = Vws + (t & 1) * NBH + vbase;
    short8 v0, v1, v2, v3, v4, v5, v6, v7;
    VLD(0); VLD(1); VLD(2); VLD(3); VLD(4); VLD(5); VLD(6); VLD(7);
    f32x4 pa0 = (f32x4){0.f, 0.f, 0.f, 0.f}, pa1 = pa0, pa2 = pa0, pa3 = pa0;
    MFMA_STEP(0, 7); MFMA_STEP(1, 6); MFMA_STEP(2, 5); MFMA_STEP(3, 4);
    MFMA_STEP(4, 3); MFMA_STEP(5, 2); MFMA_STEP(6, 1); MFMA_STEP(7, 0);

    // ---- cross-wave K-reduction via LDS
    red[0 + w][l] = pa0;
    red[4 + w][l] = pa1;
    red[8 + w][l] = pa2;
    red[12 + w][l] = pa3;
    __syncthreads();
    f32x4 fr = red[w * 4 + 0][l] + red[w * 4 + 1][l] + red[w * 4 + 2][l] + red[w * 4 + 3][l];

    // ---- gates, state update, stores
    u16* vnext = Vws + ((t + 1) & 1) * NBH;
    const long tbase = (long)t * NBH;
#pragma unroll
    for (int r = 0; r < 4; ++r) {
      float mine = fr[r];
      float other = __shfl_xor(mine, 8, 64);
      float Fi = isF ? mine : other;
      float Ri = isF ? other : mine;
      float F = sigmoidf_(Fi + pfb);
      float Rg = sigmoidf_(Ri + hwb);
      const long off = tbase + rowoff[r];
      S[r] = F * S[r] + (1.0f - F) * av[r];
      float Q = Rg * S[r] + (1.0f - Rg) * xq[r];
      if (isF) {
        out[off] = Q;                         // Y (cached store)
        if (t < TT - 1) {
          u32 word = (u32)f2bf(xn[r] + gh * Q);
          u32 othw = (u32)__shfl_xor((int)word, 1, 64);
          if ((hl & 1) == 0) {                // pack h-pair -> one dword sc1
            u32 packed = word | (othw << 16);
            STORE_U32_SC1(vnext + rowoff[r], packed);
          }
        } else {
          out[(long)TT * NBH + rowoff[r]] = Q;           // Qf
          out[(long)TT * NBH + NBH + rowoff[r]] = S[r];  // Sf
        }
      }
    }

    if (t < TT - 1) {
      // ---- drain V stores, block-join, signal; prefetch AFTER flag store
      WAITVM(0);
      __syncthreads();
      if (tid == 0) STORE_U32_SC1(flags + bk, (u32)(t + 1));
      const long nb = tbase + NBH;
      const int tn = (t + 2 < TT) ? (t + 2) : (TT - 1);
      const long nb2 = (long)tn * NBH;
#pragma unroll
      for (int r = 0; r < 4; ++r) {
        xq[r] = x[nb + rowoff[r]];
        av[r] = bf2f(A_bf[nb + rowoff[r]]);
        xn[r] = x[nb2 + rowoff[r]];
      }
    }
  }
}

extern "C" void kernel_launch(void* const* d_in, const int* in_sizes, int n_in,
                              void* d_out, int out_size, void* d_ws, size_t ws_size,
                              hipStream_t stream) {
  const float* x   = (const float*)d_in[0];
  const float* Q0  = (const float*)d_in[1];
  const float* S0  = (const float*)d_in[2];
  const float* Wih = (const float*)d_in[3];
  const float* WA  = (const float*)d_in[4];
  const float* uVr = (const float*)d_in[5];
  const float* uV2 = (const float*)d_in[6];
  const float* PFB = (const float*)d_in[7];
  const float* HWb = (const float*)d_in[8];
  float* out = (float*)d_out;

  char* ws = (char*)d_ws;
  u16* A_bf   = (u16*)(ws);                 // 67,108,864 B : A_all bf16 [T*B][HD]
  u16* Wih_bf = (u16*)(ws + 67108864);      //  4,194,304 B
  u16* Vws    = (u16*)(ws + 71303168);      //    262,144 B : ping-pong V (bf16)
  u32* flags  = (u32*)(ws + 71565312);      //        512 B : per-block step flags
  (void)in_sizes; (void)n_in; (void)out_size; (void)ws_size;

  prep_kernel<<<2048, 256, 0, stream>>>(x, Q0, Wih, uVr, uV2, Wih_bf, Vws, flags);
  agemm_kernel<<<2048, 256, 0, stream>>>(x, WA, A_bf);
  scan_kernel<<<NBLK, 256, 0, stream>>>(Wih_bf, A_bf, x, S0, PFB, HWb, uVr, uV2, Vws, out, flags);
}

// Round 5
// 2287.262 us; speedup vs baseline: 8.1502x; 1.0598x over previous
//
#include <hip/hip_runtime.h>

typedef __attribute__((ext_vector_type(8))) short short8;   // 8 bf16 in 4 VGPRs
typedef __attribute__((ext_vector_type(4))) float f32x4;
typedef unsigned short u16;
typedef unsigned int u32;

static constexpr int TT = 512;
static constexpr int HDim = 1024;
static constexpr int NBH = 64 * 1024;          // B*HD = 65536
static constexpr int NBLK = 128;               // scan blocks: 4 bg x 32 hg

__device__ __forceinline__ u16 f2bf(float f) {             // RNE f32->bf16
  u32 u = __float_as_uint(f);
  u32 r = u + 0x7FFFu + ((u >> 16) & 1u);
  return (u16)(r >> 16);
}
__device__ __forceinline__ float bf2f(u16 u) {
  return __uint_as_float(((u32)u) << 16);
}
__device__ __forceinline__ float sigmoidf_(float v) {
  return 1.0f / (1.0f + __expf(-v));
}

#define WAITVM(n) asm volatile("s_waitcnt vmcnt(" #n ")" ::: "memory")
#define SBAR() __builtin_amdgcn_sched_barrier(0)
// non-rematerializable, non-CSE-able weight load (plain cache path):
// volatile asm is pinned -> the 128 destination VGPRs stay live across the loop
#define WLD(dst, p) asm volatile("global_load_dwordx4 %0, %1, off" : "=v"(dst) : "v"(p))
// agent-coherent (sc1) ops: bypass non-coherent per-XCD L2s (L3 coherence point)
#define VLOADX4_SC1(dst, addr) \
  asm volatile("global_load_dwordx4 %0, %1, off sc1" : "=v"(dst) : "v"(addr) : "memory")
#define LOAD_U32_SC1(dst, addr) \
  asm volatile("global_load_dword %0, %1, off sc1" : "=v"(dst) : "v"(addr) : "memory")
#define STORE_U32_SC1(addr, val) \
  asm volatile("global_store_dword %0, %1, off sc1" :: "v"(addr), "v"(val) : "memory")

// ---------------- prep: Wih->bf16, V0 = x[0] + g*Q0, zero flags ------------
__global__ void prep_kernel(const float* __restrict__ x, const float* __restrict__ Q0,
                            const float* __restrict__ Wih, const float* __restrict__ uVr,
                            const float* __restrict__ uV2,
                            u16* __restrict__ Wih_bf, u16* __restrict__ V0,
                            u32* __restrict__ flags) {
  const int NW = 2048 * 1024;
  int stride = gridDim.x * blockDim.x;
  int gid = blockIdx.x * blockDim.x + threadIdx.x;
  if (gid < 2048) flags[gid] = 0u;            // 128 flag slots @ 64B stride
  for (int i = gid; i < NW; i += stride) Wih_bf[i] = f2bf(Wih[i]);
  for (int j = gid; j < NBH; j += stride) {
    int h = j & (HDim - 1);
    float g = sigmoidf_(uV2[h]) * tanhf(uVr[h]);
    V0[j] = f2bf(x[j] + g * Q0[j]);
  }
}

// ---------------- A_all = x @ WA^T  (M=32768,N=1024,K=1024), bf16 out ------
__global__ __launch_bounds__(256) void agemm_kernel(const float* __restrict__ X,
                                                    const float* __restrict__ W,
                                                    u16* __restrict__ C) {
  __shared__ u16 As[128 * 64];
  __shared__ u16 Bs[128 * 64];
  int tid = threadIdx.x;
  int l = tid & 63, w = tid >> 6;
  int n = l & 15, rowg = l >> 4;
  int wr = w >> 1, wc = w & 1;
  int bm = blockIdx.x >> 3, bn = blockIdx.x & 7;
  long m0 = (long)bm * 128;
  int n0 = bn * 128;
  int srow = tid >> 4;        // 0..15
  int sk4 = (tid & 15) * 4;   // 0..60

  f32x4 acc[4][4];
#pragma unroll
  for (int r = 0; r < 4; ++r)
#pragma unroll
    for (int c = 0; c < 4; ++c) acc[r][c] = (f32x4){0.f, 0.f, 0.f, 0.f};

  for (int kt = 0; kt < 16; ++kt) {
    __syncthreads();
#pragma unroll
    for (int i = 0; i < 8; ++i) {
      int row = srow + i * 16;
      float4 va = *(const float4*)(X + (m0 + row) * 1024 + kt * 64 + sk4);
      u32 lo = (u32)f2bf(va.x) | ((u32)f2bf(va.y) << 16);
      u32 hi = (u32)f2bf(va.z) | ((u32)f2bf(va.w) << 16);
      *(uint2*)(As + row * 64 + sk4) = make_uint2(lo, hi);
      float4 vb = *(const float4*)(W + (long)(n0 + row) * 1024 + kt * 64 + sk4);
      u32 lo2 = (u32)f2bf(vb.x) | ((u32)f2bf(vb.y) << 16);
      u32 hi2 = (u32)f2bf(vb.z) | ((u32)f2bf(vb.w) << 16);
      *(uint2*)(Bs + row * 64 + sk4) = make_uint2(lo2, hi2);
    }
    __syncthreads();
#pragma unroll
    for (int ks = 0; ks < 2; ++ks) {
      short8 af[4], bfr[4];
#pragma unroll
      for (int r = 0; r < 4; ++r)
        af[r] = *(const short8*)(As + (wr * 64 + r * 16 + n) * 64 + ks * 32 + rowg * 8);
#pragma unroll
      for (int c = 0; c < 4; ++c)
        bfr[c] = *(const short8*)(Bs + (wc * 64 + c * 16 + n) * 64 + ks * 32 + rowg * 8);
#pragma unroll
      for (int r = 0; r < 4; ++r)
#pragma unroll
        for (int c = 0; c < 4; ++c)
          acc[r][c] = __builtin_amdgcn_mfma_f32_16x16x32_bf16(af[r], bfr[c], acc[r][c], 0, 0, 0);
    }
  }
#pragma unroll
  for (int r = 0; r < 4; ++r)
#pragma unroll
    for (int c = 0; c < 4; ++c)
#pragma unroll
      for (int q = 0; q < 4; ++q) {
        long row = m0 + wr * 64 + r * 16 + rowg * 4 + q;
        int col = n0 + wc * 64 + c * 16 + n;
        C[row * 1024 + col] = f2bf(acc[r][c][q]);
      }
}

// ---------------- persistent scan ------------------------------------------
// 128 blocks = 4 batch-groups (16 rows) x 32 h-groups (32 h). Block reads only
// V[its 16 rows][all 1024 k] = 32 KB/step; sync is batch-group-local (32
// flags @64B stride). Waves K-split (256 k each); partial FR reduced via LDS.
// Weights: 32 asm-pinned short8 = 128 VGPR/wave, resident across all steps.
#define MFMA(a, b, c) __builtin_amdgcn_mfma_f32_16x16x32_bf16(a, b, c, 0, 0, 0)
#define VLDV(kk) VLOADX4_SC1(v##kk, vp + kk * 32)
#define MFMA_STEP(kk, VM)                      \
  WAITVM(VM); SBAR();                          \
  pa0 = MFMA(v##kk, b0##kk, pa0);              \
  pa1 = MFMA(v##kk, b1##kk, pa1);              \
  pa2 = MFMA(v##kk, b2##kk, pa2);              \
  pa3 = MFMA(v##kk, b3##kk, pa3);

__global__ __attribute__((amdgpu_flat_work_group_size(256, 256), amdgpu_waves_per_eu(1, 1)))
void scan_kernel(
    const u16* __restrict__ Wih_bf, const u16* __restrict__ A_bf,
    const float* __restrict__ x, const float* __restrict__ S0,
    const float* __restrict__ PFB, const float* __restrict__ HWb,
    const float* __restrict__ uVr, const float* __restrict__ uV2,
    u16* __restrict__ Vws, float* __restrict__ out, u32* __restrict__ flags) {
  const int tid = threadIdx.x, bk = blockIdx.x;
  const int bg = bk >> 5, hg = bk & 31;
  const int l = tid & 63, w = tid >> 6;
  const int n = l & 15, rowg = l >> 4;
  const int hl = n & 7;
  const int h = hg * 32 + w * 8 + hl;        // this wave's output h column
  const bool isF = (n < 8);

  __shared__ f32x4 red[16][64];              // [jt*4+wave][lane]

  const int kbase = w * 256 + rowg * 8;      // this wave's K-quarter fragment
  // weight fragments: B[k][j(n)] = Wih[j][k]; tile jt covers h = hg*32+jt*8+hl
  const u16* wp0 = Wih_bf + (long)((isF ? 0 : 1024) + hg * 32 + 0 + hl) * 1024 + kbase;
  const u16* wp1 = Wih_bf + (long)((isF ? 0 : 1024) + hg * 32 + 8 + hl) * 1024 + kbase;
  const u16* wp2 = Wih_bf + (long)((isF ? 0 : 1024) + hg * 32 + 16 + hl) * 1024 + kbase;
  const u16* wp3 = Wih_bf + (long)((isF ? 0 : 1024) + hg * 32 + 24 + hl) * 1024 + kbase;
  short8 b00, b01, b02, b03, b04, b05, b06, b07;
  short8 b10, b11, b12, b13, b14, b15, b16, b17;
  short8 b20, b21, b22, b23, b24, b25, b26, b27;
  short8 b30, b31, b32, b33, b34, b35, b36, b37;
  WLD(b00, wp0 + 0 * 32); WLD(b01, wp0 + 1 * 32); WLD(b02, wp0 + 2 * 32); WLD(b03, wp0 + 3 * 32);
  WLD(b04, wp0 + 4 * 32); WLD(b05, wp0 + 5 * 32); WLD(b06, wp0 + 6 * 32); WLD(b07, wp0 + 7 * 32);
  WLD(b10, wp1 + 0 * 32); WLD(b11, wp1 + 1 * 32); WLD(b12, wp1 + 2 * 32); WLD(b13, wp1 + 3 * 32);
  WLD(b14, wp1 + 4 * 32); WLD(b15, wp1 + 5 * 32); WLD(b16, wp1 + 6 * 32); WLD(b17, wp1 + 7 * 32);
  WLD(b20, wp2 + 0 * 32); WLD(b21, wp2 + 1 * 32); WLD(b22, wp2 + 2 * 32); WLD(b23, wp2 + 3 * 32);
  WLD(b24, wp2 + 4 * 32); WLD(b25, wp2 + 5 * 32); WLD(b26, wp2 + 6 * 32); WLD(b27, wp2 + 7 * 32);
  WLD(b30, wp3 + 0 * 32); WLD(b31, wp3 + 1 * 32); WLD(b32, wp3 + 2 * 32); WLD(b33, wp3 + 3 * 32);
  WLD(b34, wp3 + 4 * 32); WLD(b35, wp3 + 5 * 32); WLD(b36, wp3 + 6 * 32); WLD(b37, wp3 + 7 * 32);
  WAITVM(0); SBAR();

  const float pfb = PFB[h], hwb = HWb[h];
  const float gh = sigmoidf_(uV2[h]) * tanhf(uVr[h]);

  int rowoff[4];
  float S[4];
#pragma unroll
  for (int r = 0; r < 4; ++r) {
    rowoff[r] = (bg * 16 + rowg * 4 + r) * 1024 + h;
    S[r] = S0[rowoff[r]];
  }
  const int vbase = (bg * 16 + n) * 1024 + kbase;   // A-operand fragment addr
  const u32* fp = flags + ((bg * 32 + (l & 31)) << 4);  // 64B-strided flags

  float xq[4], xn[4], av[4];
#pragma unroll
  for (int r = 0; r < 4; ++r) {
    xq[r] = x[rowoff[r]];
    xn[r] = x[NBH + rowoff[r]];
    av[r] = bf2f(A_bf[rowoff[r]]);
  }

#pragma unroll 1
  for (int t = 0; t < TT; ++t) {
    // ---- wait: all 32 producers of my batch group reached step t
    if (t > 0) {
      const u32 tv = (u32)t;
      while (true) {
        u32 fv;
        LOAD_U32_SC1(fv, fp);
        WAITVM(0);
        SBAR();
        if (__all(fv >= tv)) break;
      }
    }

    // ---- partial FR over this wave's K-quarter: 8 loads all in flight
    const u16* vp = Vws + (t & 1) * NBH + vbase;
    short8 v0, v1, v2, v3, v4, v5, v6, v7;
    VLDV(0); VLDV(1); VLDV(2); VLDV(3); VLDV(4); VLDV(5); VLDV(6); VLDV(7);
    f32x4 pa0 = (f32x4){0.f, 0.f, 0.f, 0.f}, pa1 = pa0, pa2 = pa0, pa3 = pa0;
    MFMA_STEP(0, 7); MFMA_STEP(1, 6); MFMA_STEP(2, 5); MFMA_STEP(3, 4);
    MFMA_STEP(4, 3); MFMA_STEP(5, 2); MFMA_STEP(6, 1); MFMA_STEP(7, 0);

    // ---- cross-wave K-reduction via LDS (16 KB)
    red[0 + w][l] = pa0;
    red[4 + w][l] = pa1;
    red[8 + w][l] = pa2;
    red[12 + w][l] = pa3;
    __syncthreads();
    f32x4 fr = red[w * 4 + 0][l] + red[w * 4 + 1][l] + red[w * 4 + 2][l] + red[w * 4 + 3][l];

    // ---- gates, state update; V stores only (Y deferred past the flag)
    u16* vnext = Vws + ((t + 1) & 1) * NBH;
    const long tbase = (long)t * NBH;
    float Qs[4];
#pragma unroll
    for (int r = 0; r < 4; ++r) {
      float mine = fr[r];
      float other = __shfl_xor(mine, 8, 64);
      float Fi = isF ? mine : other;
      float Ri = isF ? other : mine;
      float F = sigmoidf_(Fi + pfb);
      float Rg = sigmoidf_(Ri + hwb);
      S[r] = F * S[r] + (1.0f - F) * av[r];
      float Q = Rg * S[r] + (1.0f - Rg) * xq[r];
      Qs[r] = Q;
      if (t < TT - 1) {
        u32 word = (u32)f2bf(xn[r] + gh * Q);
        u32 othw = (u32)__shfl_xor((int)word, 1, 64);
        if (isF && (hl & 1) == 0)
          STORE_U32_SC1(vnext + rowoff[r], word | (othw << 16));   // pair-packed
      }
    }

    if (t == TT - 1) {
#pragma unroll
      for (int r = 0; r < 4; ++r)
        if (isF) {
          out[tbase + rowoff[r]] = Qs[r];
          out[(long)TT * NBH + rowoff[r]] = Qs[r];            // Qf
          out[(long)TT * NBH + NBH + rowoff[r]] = S[r];       // Sf
        }
      break;
    }

    // ---- drain V stores ONLY (Y/prefetch not yet issued), block-join, signal
    WAITVM(0);
    __syncthreads();
    if (tid == 0) STORE_U32_SC1(flags + ((bg * 32 + hg) << 4), (u32)(t + 1));

    // ---- Y stores + next-step prefetch AFTER the signal (off critical path)
#pragma unroll
    for (int r = 0; r < 4; ++r)
      if (isF) out[tbase + rowoff[r]] = Qs[r];
    const long nb = tbase + NBH;
    const int tn = (t + 2 < TT) ? (t + 2) : (TT - 1);
    const long nb2 = (long)tn * NBH;
#pragma unroll
    for (int r = 0; r < 4; ++r) {
      xq[r] = x[nb + rowoff[r]];
      av[r] = bf2f(A_bf[nb + rowoff[r]]);
      xn[r] = x[nb2 + rowoff[r]];
    }
  }
}

extern "C" void kernel_launch(void* const* d_in, const int* in_sizes, int n_in,
                              void* d_out, int out_size, void* d_ws, size_t ws_size,
                              hipStream_t stream) {
  const float* x   = (const float*)d_in[0];
  const float* Q0  = (const float*)d_in[1];
  const float* S0  = (const float*)d_in[2];
  const float* Wih = (const float*)d_in[3];
  const float* WA  = (const float*)d_in[4];
  const float* uVr = (const float*)d_in[5];
  const float* uV2 = (const float*)d_in[6];
  const float* PFB = (const float*)d_in[7];
  const float* HWb = (const float*)d_in[8];
  float* out = (float*)d_out;

  char* ws = (char*)d_ws;
  u16* A_bf   = (u16*)(ws);                 // 67,108,864 B : A_all bf16 [T*B][HD]
  u16* Wih_bf = (u16*)(ws + 67108864);      //  4,194,304 B
  u16* Vws    = (u16*)(ws + 71303168);      //    262,144 B : ping-pong V (bf16)
  u32* flags  = (u32*)(ws + 71565312);      //      8,192 B : 128 flags @64B stride
  (void)in_sizes; (void)n_in; (void)out_size; (void)ws_size;

  prep_kernel<<<2048, 256, 0, stream>>>(x, Q0, Wih, uVr, uV2, Wih_bf, Vws, flags);
  agemm_kernel<<<2048, 256, 0, stream>>>(x, WA, A_bf);
  scan_kernel<<<NBLK, 256, 0, stream>>>(Wih_bf, A_bf, x, S0, PFB, HWb, uVr, uV2, Vws, out, flags);
}